// Round 8
// baseline (797.238 us; speedup 1.0000x reference)
//
#include <hip/hip_runtime.h>

#define SCALE_LORA 2.0f
// GEMM: 128x256 tile, BK=32, 8 waves (2M x 4N, 64x64 each), 32x32x16 MFMA,
// NBUF=2 (48 KiB LDS), 2 blocks/CU target (regs<=128), free-run 2-barrier tile.
#define BM 128
#define BN 256
#define BK 32

#define AS1 __attribute__((address_space(1)))
#define AS3 __attribute__((address_space(3)))

using bf16x8 = __attribute__((ext_vector_type(8))) __bf16;
using f32x4  = __attribute__((ext_vector_type(4))) float;
using f32x16 = __attribute__((ext_vector_type(16))) float;
using u16x8  = __attribute__((ext_vector_type(8))) unsigned short;

#define MFMA32(a, b, c) __builtin_amdgcn_mfma_f32_32x32x16_bf16((a), (b), (c), 0, 0, 0)

static __device__ __forceinline__ unsigned short f2bf_rne(float f) {
  unsigned int u = __builtin_bit_cast(unsigned int, f);
  u += 0x7FFFu + ((u >> 16) & 1u);   // round-to-nearest-even
  return (unsigned short)(u >> 16);
}

// ---------- kernel 1: x f32 -> bf16 (vectorized, grid-stride) ----------
__global__ void cvt_bf16_kernel(const float* __restrict__ x,
                                unsigned short* __restrict__ xb, long n) {
  long stride = (long)gridDim.x * blockDim.x;
  long nv = n >> 3;
  for (long i = (long)blockIdx.x * blockDim.x + threadIdx.x; i < nv; i += stride) {
    long base = i << 3;
    f32x4 a = *(const f32x4*)(x + base);
    f32x4 b = *(const f32x4*)(x + base + 4);
    u16x8 o;
    o[0] = f2bf_rne(a[0]); o[1] = f2bf_rne(a[1]);
    o[2] = f2bf_rne(a[2]); o[3] = f2bf_rne(a[3]);
    o[4] = f2bf_rne(b[0]); o[5] = f2bf_rne(b[1]);
    o[6] = f2bf_rne(b[2]); o[7] = f2bf_rne(b[3]);
    *(u16x8*)(xb + base) = o;
  }
}

// ---------- kernel 2: W_eff^T = (W + 2*A@B)^T as bf16, N x K ----------
__global__ void build_wt_kernel(const float* __restrict__ W,
                                const float* __restrict__ A,
                                const float* __restrict__ Bmat,
                                unsigned short* __restrict__ WT,
                                int K, int N, int R) {
  __shared__ float Bs[16][64];
  __shared__ unsigned short Tt[64][66];
  int ntn = N >> 6;
  int kt = blockIdx.x / ntn, nt = blockIdx.x - kt * ntn;
  int k0 = kt << 6, n0 = nt << 6;
  int t = threadIdx.x;
  int tx = t & 63, ty = t >> 6;

  for (int i = t; i < R * 64; i += 256)
    Bs[i >> 6][i & 63] = Bmat[(long)(i >> 6) * N + n0 + (i & 63)];
  __syncthreads();

  for (int it = 0; it < 16; ++it) {
    int kl = (it << 2) + ty;
    long kg = k0 + kl;
    float w = W[kg * N + n0 + tx];
    const float* Ar = A + kg * R;
    float s = 0.f;
    for (int r = 0; r < R; ++r) s += Ar[r] * Bs[r][tx];
    Tt[kl][tx] = f2bf_rne(w + SCALE_LORA * s);
  }
  __syncthreads();

  for (int it = 0; it < 16; ++it) {
    int nn = (it << 2) + ty;
    WT[(long)(n0 + nn) * K + k0 + tx] = Tt[tx][nn];
  }
}

// ---------- kernel 3: 2-blocks/CU 32x32-MFMA GEMM ----------
// Rows are 64 B (BK=32). Swizzle: stored granule = logical granule ^ (row&3),
// logical granule = ks*2 + (lane>>5). Applied as inverse-swizzled GLOBAL
// SOURCE (linear gload_lds dest) + swizzled ds_read addr (involution).
__global__ __launch_bounds__(512, 4) void gemm_kernel(
    const unsigned short* __restrict__ Xb,  // M x K bf16
    const unsigned short* __restrict__ WT,  // N x K bf16 (pre-transposed)
    const float* __restrict__ bias,         // N f32
    float* __restrict__ out,                // M x N f32
    int M, int N, int K)
{
  extern __shared__ unsigned short lds[];   // 48 KiB
  // A: bytes [0,16384) = 2 bufs x 8 KB; B: [16384,49152) = 2 bufs x 16 KB.

  int nwg = gridDim.x;
  int bid = blockIdx.x;
  if ((nwg & 7) == 0) {
    int cpx = nwg >> 3;
    bid = (bid & 7) * cpx + (bid >> 3);
  }
  int ntn = N / BN;                 // 16
  int tm = bid / ntn;
  int tn = bid - tm * ntn;
  const long m0 = (long)tm * BM;
  const long n0 = (long)tn * BN;

  int tid  = threadIdx.x;
  int lane = tid & 63;
  int wave = tid >> 6;
  int wr = wave >> 2;        // 0..1 : 64-row half (M)
  int wc = wave & 3;         // 0..3 : 64-col quarter (N)
  int l31 = lane & 31;
  int l3  = lane & 3;
  int g   = lane >> 5;       // 0..1

  f32x16 acc[2][2] = {};     // [fm][fn], 64 f32/lane

  // staging: thread t covers row = t>>2 (+j*128 for B), dest granule t&3,
  // source granule (t&3) ^ ((t>>2)&3)  [j*128 ≡ 0 mod 4]
  int srccol = 8 * ((tid & 3) ^ ((tid >> 2) & 3));
  const unsigned short* aSrc = Xb + (m0 + (tid >> 2)) * (long)K + srccol;
  const unsigned short* bSrc = WT + (n0 + (tid >> 2)) * (long)K + srccol;
  const int ldsByte = tid * 16;

  // fragment read offsets (bytes). slot(ks) = ((ks*2 + g) ^ l3) * 16
  const int slot0 = 16 * ((g) ^ l3);
  const int slot1 = 16 * ((2 + g) ^ l3);
  const int rowA0 = (wr * 64 + l31) * 64;
  const int rowA1 = (wr * 64 + 32 + l31) * 64;
  const int rowB0 = (wc * 64 + l31) * 64;
  const int rowB1 = (wc * 64 + 32 + l31) * 64;

  const int nt = K / BK;     // 128

  // stage tile kt into buf: A = 1 load, B = 2 loads (3 total)
#define STAGE(buf, kt) do {                                                  \
    __builtin_amdgcn_global_load_lds(                                        \
      (const AS1 void*)(aSrc + (long)(kt) * BK),                             \
      (AS3 void*)((char*)lds + (buf)*8192 + ldsByte), 16, 0, 0);             \
    _Pragma("unroll")                                                        \
    for (int j_ = 0; j_ < 2; ++j_)                                           \
      __builtin_amdgcn_global_load_lds(                                      \
        (const AS1 void*)(bSrc + j_*128*(long)K + (long)(kt) * BK),          \
        (AS3 void*)((char*)lds + 16384 + (buf)*16384 + j_*8192 + ldsByte),   \
        16, 0, 0);                                                           \
  } while (0)

#define SBAR  __builtin_amdgcn_sched_barrier(0)
#define BAR   __builtin_amdgcn_s_barrier()

  // One K-tile: top vmcnt+BAR; 8 ds_reads; MFMA ks0 (compiler counted lgkm);
  // lgkm0 + BAR rendezvous (all reads of buf done); stage t+2; MFMA ks1.
#define TILE(BUFI, VMSTR, STG) do {                                          \
    asm volatile("s_waitcnt vmcnt(" VMSTR ")" ::: "memory");                 \
    BAR;                                                                     \
    const char* Ab_ = (const char*)lds + (BUFI)*8192;                        \
    const char* Bb_ = (const char*)lds + 16384 + (BUFI)*16384;               \
    bf16x8 a00 = *(const bf16x8*)(Ab_ + rowA0 + slot0);                      \
    bf16x8 a10 = *(const bf16x8*)(Ab_ + rowA1 + slot0);                      \
    bf16x8 b00 = *(const bf16x8*)(Bb_ + rowB0 + slot0);                      \
    bf16x8 b10 = *(const bf16x8*)(Bb_ + rowB1 + slot0);                      \
    bf16x8 a01 = *(const bf16x8*)(Ab_ + rowA0 + slot1);                      \
    bf16x8 a11 = *(const bf16x8*)(Ab_ + rowA1 + slot1);                      \
    bf16x8 b01 = *(const bf16x8*)(Bb_ + rowB0 + slot1);                      \
    bf16x8 b11 = *(const bf16x8*)(Bb_ + rowB1 + slot1);                      \
    SBAR;                                                                    \
    __builtin_amdgcn_s_setprio(1);                                           \
    acc[0][0] = MFMA32(a00, b00, acc[0][0]);                                 \
    acc[0][1] = MFMA32(a00, b10, acc[0][1]);                                 \
    acc[1][0] = MFMA32(a10, b00, acc[1][0]);                                 \
    acc[1][1] = MFMA32(a10, b10, acc[1][1]);                                 \
    __builtin_amdgcn_s_setprio(0);                                           \
    SBAR;                                                                    \
    asm volatile("s_waitcnt lgkmcnt(0)" ::: "memory");                       \
    SBAR;                                                                    \
    BAR;                                                                     \
    STG;                                                                     \
    SBAR;                                                                    \
    __builtin_amdgcn_s_setprio(1);                                           \
    acc[0][0] = MFMA32(a01, b01, acc[0][0]);                                 \
    acc[0][1] = MFMA32(a01, b11, acc[0][1]);                                 \
    acc[1][0] = MFMA32(a11, b01, acc[1][0]);                                 \
    acc[1][1] = MFMA32(a11, b11, acc[1][1]);                                 \
    __builtin_amdgcn_s_setprio(0);                                           \
    SBAR;                                                                    \
  } while (0)

  // prologue: tiles 0,1 staged (6 loads in flight)
  STAGE(0, 0);
  STAGE(1, 1);

  // steady state: read buf u&1; stage u+2 into buf (u+2)&1 = u&1 after the
  // rendezvous that closes all reads of that buffer. vmcnt(3) at top leaves
  // exactly tile u+1's 3 loads in flight.
  for (int u = 0; u < nt - 2; ++u) {
    TILE(u & 1, "3", STAGE(u & 1, u + 2));
  }
  TILE(0, "3", );   // tile nt-2 (buf 0; nt-1's 3 loads stay in flight)
  TILE(1, "0", );   // tile nt-1

#undef TILE
#undef STAGE

  // epilogue: C/D layout col = lane&31, row = (reg&3) + 8*(reg>>2) + 4*g
  #pragma unroll
  for (int fn = 0; fn < 2; ++fn) {
    long col = n0 + wc * 64 + fn * 32 + l31;
    float bv = bias[col];
    #pragma unroll
    for (int fm = 0; fm < 2; ++fm) {
      long rbase = m0 + wr * 64 + fm * 32 + 4 * g;
      #pragma unroll
      for (int r = 0; r < 16; ++r) {
        long row = rbase + (r & 3) + 8 * (r >> 2);
        out[row * (long)N + col] = acc[fm][fn][r] + bv;
      }
    }
  }
}

extern "C" void kernel_launch(void* const* d_in, const int* in_sizes, int n_in,
                              void* d_out, int out_size, void* d_ws, size_t ws_size,
                              hipStream_t stream) {
  const float* x    = (const float*)d_in[0];
  const float* W    = (const float*)d_in[1];
  const float* b    = (const float*)d_in[2];
  const float* A    = (const float*)d_in[3];
  const float* Bm   = (const float*)d_in[4];

  const long D_out = in_sizes[2];                 // 4096
  const long D_in  = (long)in_sizes[1] / D_out;   // 4096
  const long M     = (long)in_sizes[0] / D_in;    // 16384
  const int  R     = (int)((long)in_sizes[3] / D_in);  // 16
  const int  K = (int)D_in, N = (int)D_out;

  unsigned short* xb = (unsigned short*)d_ws;
  unsigned short* wt = xb + (size_t)M * K;

  cvt_bf16_kernel<<<2048, 256, 0, stream>>>(x, xb, M * (long)K);
  build_wt_kernel<<<(K >> 6) * (N >> 6), 256, 0, stream>>>(W, A, Bm, wt, K, N, R);

  int grid = (int)((M / BM) * ((long)N / BN));    // 128 * 16 = 2048
  gemm_kernel<<<grid, 512, 48 * 1024, stream>>>(
      xb, wt, b, (float*)d_out, (int)M, N, K);
}